// Round 3
// baseline (166.049 us; speedup 1.0000x reference)
//
#include <hip/hip_runtime.h>
#include <hip/hip_bf16.h>

#define LATN 512
#define FINN 256
#define FOUTN 256
#define NB 16
#define HH 64
#define WW 64

typedef __attribute__((ext_vector_type(8))) short bf16x8;
typedef __attribute__((ext_vector_type(4))) float f32x4;
typedef __attribute__((ext_vector_type(4))) int i32x4;

// ------- workspace byte offsets -------
#define WS_ZERO   0           // 256 B
#define WS_MW2    4096        // 256*256*4 = 262144
#define WS_DCO    266240      // 16*256*4  = 16384
#define WS_SNORM  282624      // 16*256*4  = 16384
#define WS_WFMT   299008      // 4*294912  = 1179648
#define WS_XM     1478656     // 16*2097152 = 33554432
// xm layout  : [b][chunk(8)][pos(4096)][slot(4)] granules of 16B (8 bf16 ch), slot = iq ^ sigma(h,w)
// wfmt layout: [obi(4)][chunk(8)][tap(9)][ol(64)][slot(4)] granules, slot = iq ^ ((ol>>1)&3)

// ================= weight prep: swizzled wfmt + mw2 + zerobuf =================
__global__ void weight_prep_kernel(const float* __restrict__ weight,
                                   __hip_bfloat16* __restrict__ wfmt,
                                   float* __restrict__ mw2sum,
                                   float* __restrict__ zerobuf) {
    __shared__ float red[256];
    int o = blockIdx.x, t = threadIdx.x;
    if (o == 0 && t < 64) zerobuf[t] = 0.f;
    const float* wrow = weight + ((size_t)o * FINN + t) * 9;
    float wv[9];
    float mx = 0.f;
    #pragma unroll
    for (int k = 0; k < 9; ++k) { wv[k] = wrow[k]; mx = fmaxf(mx, fabsf(wv[k])); }
    red[t] = mx;
    __syncthreads();
    for (int k = 128; k > 0; k >>= 1) {
        if (t < k) red[t] = fmaxf(red[t], red[t + k]);
        __syncthreads();
    }
    float scale = (1.0f / 48.0f) / red[0];
    int obi = o >> 6, ol = o & 63, ch = t >> 5, il = t & 31;
    int slot = (il >> 3) ^ ((ol >> 1) & 3);
    char* base = (char*)wfmt + (size_t)obi * 294912 + (size_t)ch * 36864
               + (size_t)ol * 64 + slot * 16 + (il & 7) * 2;
    float s2 = 0.f;
    #pragma unroll
    for (int tap = 0; tap < 9; ++tap) {
        float m = wv[tap] * scale;
        s2 += m * m;
        *(__hip_bfloat16*)(base + tap * 4096) = __float2bfloat16(m);
    }
    mw2sum[(size_t)o * FINN + t] = s2;
}

// ================= fused style MLP + norm + dcoef =================
// grid = 16 (b), block = 512
__global__ __launch_bounds__(512) void style_fused_kernel(
    const float* __restrict__ lat, const float* __restrict__ ws,
    const float* __restrict__ bs, const float* __restrict__ wf,
    const float* __restrict__ bf, const float* __restrict__ mw2,
    float* __restrict__ snorm, float* __restrict__ dco) {
    __shared__ float bufA[512], bufB[512];
    int b = blockIdx.x, t = threadIdx.x;
    int jl = t >> 3, kl = t & 7;
    const float eq = 0.044194173824159216f;  // 1/sqrt(512)

    bufA[t] = lat[(size_t)b * 512 + t];
    __syncthreads();

    for (int l = 0; l < 4; ++l) {
        const float* src = (l & 1) ? bufB : bufA;
        float* dst = (l & 1) ? bufA : bufB;
        const float* wl_ = ws + (size_t)l * 512 * 512;
        const float* bl_ = bs + l * 512;
        float outv[8];
        #pragma unroll
        for (int jp = 0; jp < 8; ++jp) {
            int j = jp * 64 + jl;
            const float4* wr = (const float4*)(wl_ + (size_t)j * 512);
            float sum = 0.f;
            #pragma unroll 4
            for (int kb = 0; kb < 16; ++kb) {
                float4 v = wr[kb * 8 + kl];
                int k = kb * 32 + kl * 4;
                sum += v.x * src[k] + v.y * src[k + 1] + v.z * src[k + 2] + v.w * src[k + 3];
            }
            sum += __shfl_xor(sum, 1, 8);
            sum += __shfl_xor(sum, 2, 8);
            sum += __shfl_xor(sum, 4, 8);
            outv[jp] = sum;
        }
        if (kl == 0) {
            #pragma unroll
            for (int jp = 0; jp < 8; ++jp) {
                float v = outv[jp] * eq + bl_[jp * 64 + jl];
                dst[jp * 64 + jl] = (v < 0.f) ? 0.2f * v : v;
            }
        }
        __syncthreads();
    }
    // final linear 512 -> 256 (reads bufA)
    float sty[4];
    #pragma unroll
    for (int jp = 0; jp < 4; ++jp) {
        int j = jp * 64 + jl;
        const float4* wr = (const float4*)(wf + (size_t)j * 512);
        float sum = 0.f;
        #pragma unroll 4
        for (int kb = 0; kb < 16; ++kb) {
            float4 v = wr[kb * 8 + kl];
            int k = kb * 32 + kl * 4;
            sum += v.x * bufA[k] + v.y * bufA[k + 1] + v.z * bufA[k + 2] + v.w * bufA[k + 3];
        }
        sum += __shfl_xor(sum, 1, 8);
        sum += __shfl_xor(sum, 2, 8);
        sum += __shfl_xor(sum, 4, 8);
        sty[jp] = sum + bf[jp * 64 + jl];
    }
    __syncthreads();
    if (kl == 0) {
        #pragma unroll
        for (int jp = 0; jp < 4; ++jp) bufB[jp * 64 + jl] = sty[jp];
    }
    __syncthreads();
    // inf-norm over 256
    if (t < 256) bufA[t] = fabsf(bufB[t]);
    __syncthreads();
    for (int k = 128; k > 0; k >>= 1) {
        if (t < k) bufA[t] = fmaxf(bufA[t], bufA[t + k]);
        __syncthreads();
    }
    float inv = 1.0f / bufA[0];
    __syncthreads();
    if (t < 256) {
        float sv = bufB[t] * inv;
        snorm[(size_t)b * FINN + t] = sv;
        bufA[t] = sv * sv;
    }
    __syncthreads();
    // dcoef: per o, sum_i mw2[o][i]*s[i]^2
    #pragma unroll
    for (int jp = 0; jp < 4; ++jp) {
        int o = jp * 64 + jl;
        const float4* m2 = (const float4*)(mw2 + (size_t)o * 256);
        float sum = 0.f;
        #pragma unroll
        for (int kb = 0; kb < 8; ++kb) {
            float4 v = m2[kb * 8 + kl];
            int k = kb * 32 + kl * 4;
            sum += v.x * bufA[k] + v.y * bufA[k + 1] + v.z * bufA[k + 2] + v.w * bufA[k + 3];
        }
        sum += __shfl_xor(sum, 1, 8);
        sum += __shfl_xor(sum, 2, 8);
        sum += __shfl_xor(sum, 4, 8);
        if (kl == 0) dco[(size_t)b * FOUTN + o] = rsqrtf(sum + 1e-8f);
    }
}

// ================= x NCHW fp32 -> swizzled chunk-major bf16 xm =================
// grid (64 h, 16 b), block 256
__global__ __launch_bounds__(256) void xcvt_kernel(const float* __restrict__ x,
                                                   const float* __restrict__ sn,
                                                   char* __restrict__ xm) {
    __shared__ float tile[64][65];
    int h = blockIdx.x, b = blockIdx.y;
    int t = threadIdx.x;
    int wl_ = t & 63, ig = t >> 6;
    char* xmb = xm + (size_t)b * 2097152;
    for (int icb = 0; icb < 4; ++icb) {
        if (icb) __syncthreads();
        #pragma unroll
        for (int p = 0; p < 16; ++p) {
            int i_l = p * 4 + ig;
            int i = icb * 64 + i_l;
            tile[i_l][wl_] = x[((size_t)(b * FINN + i)) * 4096 + h * 64 + wl_]
                             * sn[(size_t)b * FINN + i];
        }
        __syncthreads();
        #pragma unroll
        for (int rep = 0; rep < 2; ++rep) {
            int g = rep * 256 + t;     // 0..511
            int w = g >> 3, q8 = g & 7;
            int chunk = icb * 2 + (q8 >> 2), iq = q8 & 3;
            int slot = iq ^ (((h + 1) + ((w + 1) >> 1)) & 3);
            short tmp[8];
            #pragma unroll
            for (int j = 0; j < 8; ++j) {
                __hip_bfloat16 hb = __float2bfloat16(tile[q8 * 8 + j][w]);
                tmp[j] = *(short*)&hb;
            }
            char* dst = xmb + (size_t)chunk * 262144 + (size_t)(h * 64 + w) * 64 + slot * 16;
            *(bf16x8*)dst = *(bf16x8*)tmp;
        }
    }
}

// ================= global_load_lds helper =================
__device__ __forceinline__ void gl_lds16(const void* g, void* l) {
    __builtin_amdgcn_global_load_lds(
        (const __attribute__((address_space(1))) unsigned int*)g,
        (__attribute__((address_space(3))) unsigned int*)l, 16, 0, 0);
}

// ================= MFMA conv =================
// grid (8 htile, 4 obi, 16 b), 512 threads (8 waves).
// Block tile: O=64 x 8 rows x 64 w; wave wid owns row h0+wid, 4x4 frags of 16x16x32.
__global__ __launch_bounds__(512, 4) void mconv_kernel(
    const char* __restrict__ xm, const char* __restrict__ wfmt,
    const float* __restrict__ dco, const float* __restrict__ zerobuf,
    float* __restrict__ y) {
    __shared__ char xs[42240];   // 10 rows x 66 cols x 64B (pos-major, swizzled slots)
    __shared__ char wl[36864];   // [tap 9][o 64][slot 4] granules

    int t = threadIdx.x;
    int lane = t & 63;
    int wid = t >> 6;
    int h0 = blockIdx.x * 8;
    int obi = blockIdx.y;
    int b = blockIdx.z;

    // zero halo columns (c=0, c=65) once; never overwritten by staging
    if (t < 80) {
        int r = t >> 3, sub = t & 7;
        int col = (sub >> 2) * 65, slot = sub & 3;
        *(i32x4*)(xs + ((r * 66 + col) * 4 + slot) * 16) = (i32x4){0, 0, 0, 0};
    }

    // x staging: 40 issues/chunk (10 rows x 4 quarters), 5 per wave
    const char* xmb = xm + (size_t)b * 2097152;
    const char* xsrc[5];
    unsigned xinc[5];
    unsigned xdst[5];
    #pragma unroll
    for (int q = 0; q < 5; ++q) {
        int idx = wid * 5 + q;
        int r = idx >> 2, quarter = idx & 3;
        int gh = h0 - 1 + r;
        bool v = (gh >= 0) && (gh < HH);
        xsrc[q] = v ? xmb + (size_t)(gh * 64 + quarter * 16) * 64 + lane * 16
                    : (const char*)zerobuf;
        xinc[q] = v ? 262144u : 0u;
        xdst[q] = (unsigned)((r * 66 + 1) * 64 + quarter * 1024);
    }
    // w staging: 36 issues/chunk; waves 0..3 take 5, waves 4..7 take 4
    const char* wlane = wfmt + (size_t)obi * 294912 + lane * 16;

    f32x4 acc[4][4] = {};
    int l15 = lane & 15, lg = lane >> 4;
    int wfrag = l15 * 64 + ((lg ^ ((l15 >> 1) & 3)) << 4);

    for (int ch = 0; ch < 8; ++ch) {
        if (ch) __syncthreads();
        #pragma unroll
        for (int q = 0; q < 5; ++q) {
            gl_lds16(xsrc[q], xs + xdst[q]);
            xsrc[q] += xinc[q];
        }
        #pragma unroll
        for (int q = 0; q < 5; ++q) {
            int idx = wid + q * 8;
            if (idx < 36)
                gl_lds16(wlane + idx * 1024, wl + idx * 1024);
        }
        wlane += 36864;
        __syncthreads();
        #pragma unroll
        for (int kh = 0; kh < 3; ++kh) {
            #pragma unroll
            for (int kw = 0; kw < 3; ++kw) {
                int tap = kh * 3 + kw;
                int pos0 = (wid + kh) * 66 + kw + l15;
                int xb_off = pos0 * 64 + ((lg ^ ((pos0 >> 1) & 3)) << 4);
                bf16x8 bfr[4];
                #pragma unroll
                for (int nt = 0; nt < 4; ++nt)
                    bfr[nt] = *(const bf16x8*)(xs + xb_off + nt * 1024);
                #pragma unroll
                for (int mt = 0; mt < 4; ++mt) {
                    bf16x8 af = *(const bf16x8*)(wl + tap * 4096 + mt * 1024 + wfrag);
                    #pragma unroll
                    for (int nt = 0; nt < 4; ++nt)
                        acc[mt][nt] = __builtin_amdgcn_mfma_f32_16x16x32_bf16(
                            af, bfr[nt], acc[mt][nt], 0, 0, 0);
                }
            }
        }
    }

    // epilogue: demod + store
    const float* dcb = dco + (size_t)b * FOUTN + obi * 64;
    float* yb = y + (((size_t)b * FOUTN + obi * 64) * HH + (h0 + wid)) * WW;
    #pragma unroll
    for (int mt = 0; mt < 4; ++mt) {
        #pragma unroll
        for (int j = 0; j < 4; ++j) {
            int o_l = mt * 16 + lg * 4 + j;
            float d = dcb[o_l];
            #pragma unroll
            for (int nt = 0; nt < 4; ++nt)
                yb[(size_t)o_l * 4096 + nt * 16 + l15] = acc[mt][nt][j] * d;
        }
    }
}

extern "C" void kernel_launch(void* const* d_in, const int* in_sizes, int n_in,
                              void* d_out, int out_size, void* d_ws, size_t ws_size,
                              hipStream_t stream) {
    const float* x      = (const float*)d_in[0];
    const float* lat    = (const float*)d_in[1];
    const float* weight = (const float*)d_in[2];
    const float* ws     = (const float*)d_in[3];
    const float* bs     = (const float*)d_in[4];
    const float* wf     = (const float*)d_in[5];
    const float* bf     = (const float*)d_in[6];
    float* y = (float*)d_out;

    char* base = (char*)d_ws;
    float* zerobuf = (float*)(base + WS_ZERO);
    float* mw2     = (float*)(base + WS_MW2);
    float* dco     = (float*)(base + WS_DCO);
    float* snorm   = (float*)(base + WS_SNORM);
    __hip_bfloat16* wfmt = (__hip_bfloat16*)(base + WS_WFMT);
    char* xm       = base + WS_XM;

    weight_prep_kernel<<<FOUTN, 256, 0, stream>>>(weight, wfmt, mw2, zerobuf);
    style_fused_kernel<<<NB, 512, 0, stream>>>(lat, ws, bs, wf, bf, mw2, snorm, dco);
    xcvt_kernel<<<dim3(HH, NB), 256, 0, stream>>>(x, snorm, xm);
    mconv_kernel<<<dim3(8, 4, NB), 512, 0, stream>>>(xm, (const char*)wfmt, dco, zerobuf, y);
}

// Round 4
// 128.533 us; speedup vs baseline: 1.2919x; 1.2919x over previous
//
#include <hip/hip_runtime.h>
#include <hip/hip_bf16.h>

#define LATN 512
#define FINN 256
#define FOUTN 256
#define NB 16
#define HH 64
#define WW 64

typedef __attribute__((ext_vector_type(8))) short bf16x8;
typedef __attribute__((ext_vector_type(4))) float f32x4;
typedef __attribute__((ext_vector_type(4))) int i32x4;

// ------- workspace byte offsets -------
#define WS_ZERO   0           // 256 B
#define WS_MW2    4096        // 256*256*4 = 262144
#define WS_DCO    266240      // 16*256*4  = 16384
#define WS_SNORM  282624      // 16*256*4  = 16384
#define WS_WFMT   299008      // 4*294912  = 1179648
#define WS_XM     1478656     // 16*2097152 = 33554432
// style ping-pong buffers ALIAS the xm region (dead until xcvt runs):
#define WS_HA     (WS_XM)            // 16*512*4 = 32768
#define WS_HB     (WS_XM + 32768)    // 16*512*4 = 32768
#define WS_STY    (WS_XM + 65536)    // 16*256*4 = 16384
// xm layout  : [b][chunk(8)][pos(4096)][slot(4)] granules of 16B (8 bf16 ch), slot = iq ^ sigma(h,w)
// wfmt layout: [obi(4)][chunk(8)][tap(9)][ol(64)][slot(4)] granules, slot = iq ^ ((ol>>1)&3)

// ================= weight prep: swizzled wfmt + mw2 + zerobuf =================
__global__ void weight_prep_kernel(const float* __restrict__ weight,
                                   __hip_bfloat16* __restrict__ wfmt,
                                   float* __restrict__ mw2sum,
                                   float* __restrict__ zerobuf) {
    __shared__ float red[256];
    int o = blockIdx.x, t = threadIdx.x;
    if (o == 0 && t < 64) zerobuf[t] = 0.f;
    const float* wrow = weight + ((size_t)o * FINN + t) * 9;
    float wv[9];
    float mx = 0.f;
    #pragma unroll
    for (int k = 0; k < 9; ++k) { wv[k] = wrow[k]; mx = fmaxf(mx, fabsf(wv[k])); }
    red[t] = mx;
    __syncthreads();
    for (int k = 128; k > 0; k >>= 1) {
        if (t < k) red[t] = fmaxf(red[t], red[t + k]);
        __syncthreads();
    }
    float scale = (1.0f / 48.0f) / red[0];
    int obi = o >> 6, ol = o & 63, ch = t >> 5, il = t & 31;
    int slot = (il >> 3) ^ ((ol >> 1) & 3);
    char* base = (char*)wfmt + (size_t)obi * 294912 + (size_t)ch * 36864
               + (size_t)ol * 64 + slot * 16 + (il & 7) * 2;
    float s2 = 0.f;
    #pragma unroll
    for (int tap = 0; tap < 9; ++tap) {
        float m = wv[tap] * scale;
        s2 += m * m;
        *(__hip_bfloat16*)(base + tap * 4096) = __float2bfloat16(m);
    }
    mw2sum[(size_t)o * FINN + t] = s2;
}

// ================= style MLP layer (parallel over j across blocks) =================
// grid = (out_dim/16, B), block = 256. 16 lanes per output j, float4 K-loads.
__global__ __launch_bounds__(256) void style_layer_kernel(
    const float* __restrict__ in, const float* __restrict__ w,
    const float* __restrict__ bias, float* __restrict__ out,
    int in_dim_v4, int out_dim, float scale, int do_lrelu) {
    int t = threadIdx.x;
    int jl = t >> 4, kl = t & 15;
    int j = blockIdx.x * 16 + jl;
    int b = blockIdx.y;
    const float4* inr = (const float4*)(in + (size_t)b * (in_dim_v4 * 4));
    const float4* wr  = (const float4*)(w + (size_t)j * (in_dim_v4 * 4));
    float sum = 0.f;
    #pragma unroll 4
    for (int kb = kl; kb < in_dim_v4; kb += 16) {
        float4 wv = wr[kb], iv = inr[kb];
        sum += wv.x * iv.x + wv.y * iv.y + wv.z * iv.z + wv.w * iv.w;
    }
    #pragma unroll
    for (int off = 8; off >= 1; off >>= 1)
        sum += __shfl_xor(sum, off, 16);
    if (kl == 0) {
        float v = sum * scale + bias[j];
        if (do_lrelu && v < 0.f) v *= 0.2f;
        out[(size_t)b * out_dim + j] = v;
    }
}

// ================= fused inf-norm + dcoef =================
// grid = B, block = 256 (thread = channel/output index)
__global__ __launch_bounds__(256) void norm_dcoef_kernel(
    const float* __restrict__ sty, const float* __restrict__ mw2,
    float* __restrict__ snorm, float* __restrict__ dco) {
    __shared__ float red[256];
    __shared__ float s2[256];
    int b = blockIdx.x, t = threadIdx.x;
    float v = sty[(size_t)b * FINN + t];
    red[t] = fabsf(v);
    __syncthreads();
    for (int k = 128; k > 0; k >>= 1) {
        if (t < k) red[t] = fmaxf(red[t], red[t + k]);
        __syncthreads();
    }
    float sv = v / red[0];
    snorm[(size_t)b * FINN + t] = sv;
    s2[t] = sv * sv;
    __syncthreads();
    const float4* m2 = (const float4*)(mw2 + (size_t)t * FINN);
    const float4* sq = (const float4*)s2;
    float sum = 0.f;
    #pragma unroll 8
    for (int kb = 0; kb < 64; ++kb) {
        float4 a = m2[kb], xq = sq[kb];
        sum += a.x * xq.x + a.y * xq.y + a.z * xq.z + a.w * xq.w;
    }
    dco[(size_t)b * FOUTN + t] = rsqrtf(sum + 1e-8f);
}

// ================= x NCHW fp32 -> swizzled chunk-major bf16 xm =================
// grid (64 h, 16 b), block 256
__global__ __launch_bounds__(256) void xcvt_kernel(const float* __restrict__ x,
                                                   const float* __restrict__ sn,
                                                   char* __restrict__ xm) {
    __shared__ float tile[64][65];
    int h = blockIdx.x, b = blockIdx.y;
    int t = threadIdx.x;
    int wl_ = t & 63, ig = t >> 6;
    char* xmb = xm + (size_t)b * 2097152;
    for (int icb = 0; icb < 4; ++icb) {
        if (icb) __syncthreads();
        #pragma unroll
        for (int p = 0; p < 16; ++p) {
            int i_l = p * 4 + ig;
            int i = icb * 64 + i_l;
            tile[i_l][wl_] = x[((size_t)(b * FINN + i)) * 4096 + h * 64 + wl_]
                             * sn[(size_t)b * FINN + i];
        }
        __syncthreads();
        #pragma unroll
        for (int rep = 0; rep < 2; ++rep) {
            int g = rep * 256 + t;     // 0..511
            int w = g >> 3, q8 = g & 7;
            int chunk = icb * 2 + (q8 >> 2), iq = q8 & 3;
            int slot = iq ^ (((h + 1) + ((w + 1) >> 1)) & 3);
            short tmp[8];
            #pragma unroll
            for (int j = 0; j < 8; ++j) {
                __hip_bfloat16 hb = __float2bfloat16(tile[q8 * 8 + j][w]);
                tmp[j] = *(short*)&hb;
            }
            char* dst = xmb + (size_t)chunk * 262144 + (size_t)(h * 64 + w) * 64 + slot * 16;
            *(bf16x8*)dst = *(bf16x8*)tmp;
        }
    }
}

// ================= global_load_lds helper =================
__device__ __forceinline__ void gl_lds16(const void* g, void* l) {
    __builtin_amdgcn_global_load_lds(
        (const __attribute__((address_space(1))) unsigned int*)g,
        (__attribute__((address_space(3))) unsigned int*)l, 16, 0, 0);
}

// ================= MFMA conv =================
// grid (8 htile, 4 obi, 16 b), 512 threads (8 waves).
// Block tile: O=64 x 8 rows x 64 w; wave wid owns row h0+wid, 4x4 frags of 16x16x32.
__global__ __launch_bounds__(512, 4) void mconv_kernel(
    const char* __restrict__ xm, const char* __restrict__ wfmt,
    const float* __restrict__ dco, const float* __restrict__ zerobuf,
    float* __restrict__ y) {
    __shared__ char xs[42240];   // 10 rows x 66 cols x 64B (pos-major, swizzled slots)
    __shared__ char wl[36864];   // [tap 9][o 64][slot 4] granules

    int t = threadIdx.x;
    int lane = t & 63;
    int wid = t >> 6;
    int h0 = blockIdx.x * 8;
    int obi = blockIdx.y;
    int b = blockIdx.z;

    // zero halo columns (c=0, c=65) once; never overwritten by staging
    if (t < 80) {
        int r = t >> 3, sub = t & 7;
        int col = (sub >> 2) * 65, slot = sub & 3;
        *(i32x4*)(xs + ((r * 66 + col) * 4 + slot) * 16) = (i32x4){0, 0, 0, 0};
    }

    // x staging: 40 issues/chunk (10 rows x 4 quarters), 5 per wave
    const char* xmb = xm + (size_t)b * 2097152;
    const char* xsrc[5];
    unsigned xinc[5];
    unsigned xdst[5];
    #pragma unroll
    for (int q = 0; q < 5; ++q) {
        int idx = wid * 5 + q;
        int r = idx >> 2, quarter = idx & 3;
        int gh = h0 - 1 + r;
        bool v = (gh >= 0) && (gh < HH);
        xsrc[q] = v ? xmb + (size_t)(gh * 64 + quarter * 16) * 64 + lane * 16
                    : (const char*)zerobuf;
        xinc[q] = v ? 262144u : 0u;
        xdst[q] = (unsigned)((r * 66 + 1) * 64 + quarter * 1024);
    }
    // w staging: 36 issues/chunk; waves 0..3 take 5, waves 4..7 take 4
    const char* wlane = wfmt + (size_t)obi * 294912 + lane * 16;

    f32x4 acc[4][4] = {};
    int l15 = lane & 15, lg = lane >> 4;
    int wfrag = l15 * 64 + ((lg ^ ((l15 >> 1) & 3)) << 4);

    for (int ch = 0; ch < 8; ++ch) {
        if (ch) __syncthreads();
        #pragma unroll
        for (int q = 0; q < 5; ++q) {
            gl_lds16(xsrc[q], xs + xdst[q]);
            xsrc[q] += xinc[q];
        }
        #pragma unroll
        for (int q = 0; q < 5; ++q) {
            int idx = wid + q * 8;
            if (idx < 36)
                gl_lds16(wlane + idx * 1024, wl + idx * 1024);
        }
        wlane += 36864;
        __syncthreads();
        #pragma unroll
        for (int kh = 0; kh < 3; ++kh) {
            #pragma unroll
            for (int kw = 0; kw < 3; ++kw) {
                int tap = kh * 3 + kw;
                int pos0 = (wid + kh) * 66 + kw + l15;
                int xb_off = pos0 * 64 + ((lg ^ ((pos0 >> 1) & 3)) << 4);
                bf16x8 bfr[4];
                #pragma unroll
                for (int nt = 0; nt < 4; ++nt)
                    bfr[nt] = *(const bf16x8*)(xs + xb_off + nt * 1024);
                #pragma unroll
                for (int mt = 0; mt < 4; ++mt) {
                    bf16x8 af = *(const bf16x8*)(wl + tap * 4096 + mt * 1024 + wfrag);
                    #pragma unroll
                    for (int nt = 0; nt < 4; ++nt)
                        acc[mt][nt] = __builtin_amdgcn_mfma_f32_16x16x32_bf16(
                            af, bfr[nt], acc[mt][nt], 0, 0, 0);
                }
            }
        }
    }

    // epilogue: demod + store
    const float* dcb = dco + (size_t)b * FOUTN + obi * 64;
    float* yb = y + (((size_t)b * FOUTN + obi * 64) * HH + (h0 + wid)) * WW;
    #pragma unroll
    for (int mt = 0; mt < 4; ++mt) {
        #pragma unroll
        for (int j = 0; j < 4; ++j) {
            int o_l = mt * 16 + lg * 4 + j;
            float d = dcb[o_l];
            #pragma unroll
            for (int nt = 0; nt < 4; ++nt)
                yb[(size_t)o_l * 4096 + nt * 16 + l15] = acc[mt][nt][j] * d;
        }
    }
}

extern "C" void kernel_launch(void* const* d_in, const int* in_sizes, int n_in,
                              void* d_out, int out_size, void* d_ws, size_t ws_size,
                              hipStream_t stream) {
    const float* x      = (const float*)d_in[0];
    const float* lat    = (const float*)d_in[1];
    const float* weight = (const float*)d_in[2];
    const float* ws     = (const float*)d_in[3];
    const float* bs     = (const float*)d_in[4];
    const float* wf     = (const float*)d_in[5];
    const float* bf     = (const float*)d_in[6];
    float* y = (float*)d_out;

    char* base = (char*)d_ws;
    float* zerobuf = (float*)(base + WS_ZERO);
    float* mw2     = (float*)(base + WS_MW2);
    float* dco     = (float*)(base + WS_DCO);
    float* snorm   = (float*)(base + WS_SNORM);
    __hip_bfloat16* wfmt = (__hip_bfloat16*)(base + WS_WFMT);
    char* xm       = base + WS_XM;
    float* hA      = (float*)(base + WS_HA);
    float* hB      = (float*)(base + WS_HB);
    float* sty     = (float*)(base + WS_STY);

    const float eq = 0.044194173824159216f;  // 1/sqrt(512)

    weight_prep_kernel<<<FOUTN, 256, 0, stream>>>(weight, wfmt, mw2, zerobuf);
    // style MLP: 4 EqualLinear+LeakyReLU (parallel over j), then final linear
    style_layer_kernel<<<dim3(LATN / 16, NB), 256, 0, stream>>>(
        lat, ws + 0 * (size_t)LATN * LATN, bs + 0 * LATN, hA, LATN / 4, LATN, eq, 1);
    style_layer_kernel<<<dim3(LATN / 16, NB), 256, 0, stream>>>(
        hA, ws + 1 * (size_t)LATN * LATN, bs + 1 * LATN, hB, LATN / 4, LATN, eq, 1);
    style_layer_kernel<<<dim3(LATN / 16, NB), 256, 0, stream>>>(
        hB, ws + 2 * (size_t)LATN * LATN, bs + 2 * LATN, hA, LATN / 4, LATN, eq, 1);
    style_layer_kernel<<<dim3(LATN / 16, NB), 256, 0, stream>>>(
        hA, ws + 3 * (size_t)LATN * LATN, bs + 3 * LATN, hB, LATN / 4, LATN, eq, 1);
    style_layer_kernel<<<dim3(FINN / 16, NB), 256, 0, stream>>>(
        hB, wf, bf, sty, LATN / 4, FINN, 1.0f, 0);
    // inf-norm + dcoef (styles ping-pong buffers are dead after this point)
    norm_dcoef_kernel<<<NB, 256, 0, stream>>>(sty, mw2, snorm, dco);
    // x conversion (overwrites the aliased style buffers — safe now)
    xcvt_kernel<<<dim3(HH, NB), 256, 0, stream>>>(x, snorm, xm);
    // MFMA conv
    mconv_kernel<<<dim3(8, 4, NB), 512, 0, stream>>>(xm, (const char*)wfmt, dco, zerobuf, y);
}